// Round 11
// baseline (2005.573 us; speedup 1.0000x reference)
//
#include <hip/hip_runtime.h>
#include <cstdint>

#define B_SZ   2048
#define T_SZ   80
#define VOCABN 80
#define EMBN   8
#define HID    256
#define G4     1024
#define NTHR   512

typedef __bf16 bf16;
typedef __attribute__((ext_vector_type(8))) __bf16 bf16x8;
typedef __attribute__((ext_vector_type(4))) float  f32x4;
typedef __attribute__((ext_vector_type(4))) unsigned short u16x4;

__device__ __forceinline__ float sigf(float x)   { return 1.0f / (1.0f + __expf(-x)); }
__device__ __forceinline__ float tanhf2(float x) { return 1.0f - 2.0f / (__expf(2.0f * x) + 1.0f); }

__device__ __forceinline__ unsigned short f2bf(float f) {
    union { float f; unsigned int u; } v; v.f = f;
    unsigned int u = v.u;
    return (unsigned short)((u + 0x7FFFu + ((u >> 16) & 1u)) >> 16);
}
__device__ __forceinline__ float bf2f(unsigned short h) {
    union { unsigned int u; float f; } v; v.u = ((unsigned int)h) << 16;
    return v.f;
}

// Swizzled h-tile (verified R1-R10): [16][256] bf16, 16B blocks rotated by 2*row.
#define HSWZ(row, col) ((row) * 256 + (((((col) >> 3) + 2 * (row)) & 31) << 3) + ((col) & 7))
// A-fragment read (verified): A-rows = lc, k-cols (k*32 + lg*8 .. +8)
#define AFRAG(hptr, k_) (*(const bf16x8*)&(hptr)[lc * 256 + (((4 * (k_) + lg + 2 * lc) & 31) << 3)])

// ===================== ws layout (main path) =====================
#define WPA_OFF  0ull                      // 512 KB  W1h  [k8][nt64][lane64][8]
#define WPG_OFF  524288ull                 // 512 KB  W2x
#define WPB_OFF  1048576ull                // 512 KB  W2h
#define W1X_OFF  1572864ull                // 64 KB   W1x K=32 frag (zeros for lg>0)
#define C1G_OFF  1638400ull                // 2 MB    c1 state f32 [2048][256]
#define C2G_OFF  3735552ull                // 2 MB    c2 state f32
#define H2P_OFF  5832704ull                // 1 MB    h2 state bf16 [2048][256]
#define H1C_OFF  6881280ull                // TC*1MB  h1c [b][dt][256] bf16
#define FIXED_WS 6881280ull
#define PER_TC   5242880ull                // 1MB h1c + 4MB gxc per t

// ===================== prep: gate-tile packed weights =====================
// nt = w*8 + hf*4 + g ; scol = g*256 + w*32 + hf*16 + lc
__global__ void prep_all(const float* __restrict__ W1, const float* __restrict__ W2,
                         unsigned short* __restrict__ wpA, unsigned short* __restrict__ wpG,
                         unsigned short* __restrict__ wpB, unsigned short* __restrict__ w1xg) {
    int idx = blockIdx.x * blockDim.x + threadIdx.x;
    if (idx < 3 * 8 * 64 * 64) {
        int s = idx >> 15, rem = idx & 32767;
        int k = rem >> 12, nt = (rem >> 6) & 63, lane = rem & 63;
        int lc = lane & 15, lg = lane >> 4;
        int scol = (nt & 3) * 256 + (nt >> 3) * 32 + ((nt >> 2) & 1) * 16 + lc;
        unsigned short* dst = (s == 0) ? wpA : (s == 1 ? wpG : wpB);
#pragma unroll
        for (int e = 0; e < 8; ++e) {
            int row = k * 32 + lg * 8 + e;
            float val = (s == 0) ? W1[(EMBN + row) * G4 + scol]
                      : (s == 1) ? W2[row * G4 + scol]
                                 : W2[(256 + row) * G4 + scol];
            dst[rem * 8 + e] = f2bf(val);
        }
    } else if (idx < 3 * 8 * 64 * 64 + 64 * 64) {
        int i = idx - 3 * 8 * 64 * 64;
        int nt = i >> 6, lane = i & 63;
        int lc = lane & 15, lg = lane >> 4;
        int scol = (nt & 3) * 256 + (nt >> 3) * 32 + ((nt >> 2) & 1) * 16 + lc;
#pragma unroll
        for (int e = 0; e < 8; ++e)
            w1xg[i * 8 + e] = (lg == 0) ? f2bf(W1[e * G4 + scol]) : (unsigned short)0;
    }
}

// ===================== kernel A: layer-1 recurrence (time chunk) =====================
// amdgpu_waves_per_eu(2,2): LDS already caps us at 8 waves/CU (2/EU); tell the
// register allocator so it budgets 256 VGPRs instead of spilling wreg[48] at 128.
__global__ __launch_bounds__(NTHR) __attribute__((amdgpu_waves_per_eu(2, 2)))
void lstm_l1(const int* __restrict__ feat,
             const bf16x8* __restrict__ wpA, const bf16x8* __restrict__ w1xg,
             const float* __restrict__ emb, const float* __restrict__ b1,
             unsigned short* __restrict__ h1c, float* __restrict__ c1g,
             int t0, int TC)
{
    __shared__ __align__(16) bf16 wlds[2 * 4096 * 8];     // 128 KB: slices k=6,7
    __shared__ __align__(16) bf16 h1s[2][16 * 256];       // 16 KB (rows 8..15 stay 0)
    __shared__ __align__(16) bf16 embl[VOCABN * 8];
    __shared__ unsigned char toks8[8 * T_SZ];

    const int tid  = threadIdx.x;
    const int lane = tid & 63;
    const int wid  = tid >> 6;
    const int lc   = lane & 15;
    const int lg   = lane >> 4;
    const int bblk = blockIdx.x;
    const int b0   = bblk * 8;
    const int t1   = t0 + TC;

    for (int i = tid; i < 2 * 16 * 256; i += NTHR) h1s[0][i] = (bf16)0.0f;
    for (int i = tid; i < VOCABN * 8; i += NTHR) ((unsigned short*)embl)[i] = f2bf(emb[i]);
    for (int i = tid; i < 8 * T_SZ; i += NTHR) {
        int r = i / T_SZ, t = i - r * T_SZ;
        toks8[i] = (unsigned char)feat[(b0 + r) * T_SZ + t];
    }
    {
        bf16x8* wv = (bf16x8*)wlds;
        for (int i = tid; i < 2 * 4096; i += NTHR) wv[i] = wpA[6 * 4096 + i];
    }
    float c1[2][4] = {{0.f,0.f,0.f,0.f},{0.f,0.f,0.f,0.f}};
    if (t0 > 0) {
        __syncthreads();   // zero-fill done before h_prev overwrite
        for (int i = tid; i < 256; i += NTHR) {            // 8 rows x 32 vec8
            int row = i >> 5, col0 = (i & 31) << 3;
            bf16x8 v = *(const bf16x8*)&h1c[((size_t)(b0 + row) * TC + (TC - 1)) * 256 + col0];
            *(bf16x8*)&h1s[0][HSWZ(row, col0)] = v;
        }
        if (lg < 2) {
#pragma unroll
            for (int hf = 0; hf < 2; ++hf)
#pragma unroll
                for (int r = 0; r < 4; ++r)
                    c1[hf][r] = c1g[(size_t)(b0 + lg * 4 + r) * 256 + wid * 32 + hf * 16 + lc];
        }
    }
    __syncthreads();

    bf16x8 wreg[48];
#pragma unroll
    for (int k = 0; k < 6; ++k)
#pragma unroll
        for (int j = 0; j < 8; ++j)
            wreg[k * 8 + j] = wpA[(k * 64 + wid * 8 + j) * 64 + lane];

    float b1v[2][4];
#pragma unroll
    for (int hf = 0; hf < 2; ++hf)
#pragma unroll
        for (int g = 0; g < 4; ++g)
            b1v[hf][g] = b1[g * 256 + wid * 32 + hf * 16 + lc];

    const f32x4 zf = {0.f, 0.f, 0.f, 0.f};
    const bf16x8* wldsv = (const bf16x8*)wlds;

    for (int t = t0; t < t1; ++t) {
        const int rb_ = t & 1;
        const bf16* hr = h1s[rb_];
        bf16* hw = h1s[rb_ ^ 1];

        bf16x8 ax;
        for (int e = 0; e < 8; ++e) ax[e] = (bf16)0.0f;
        if (lg == 0) ax = *(const bf16x8*)&embl[(int)toks8[(lc & 7) * T_SZ + t] * 8];

#pragma unroll
        for (int hf = 0; hf < 2; ++hf) {
            f32x4 a4[4];
#pragma unroll
            for (int g = 0; g < 4; ++g) a4[g] = zf;
#pragma unroll
            for (int g = 0; g < 4; ++g) {
                bf16x8 xw = w1xg[(wid * 8 + hf * 4 + g) * 64 + lane];
                a4[g] = __builtin_amdgcn_mfma_f32_16x16x32_bf16(ax, xw, a4[g], 0, 0, 0);
            }
#pragma unroll
            for (int k = 0; k < 6; ++k) {
                bf16x8 afr = AFRAG(hr, k);
#pragma unroll
                for (int g = 0; g < 4; ++g)
                    a4[g] = __builtin_amdgcn_mfma_f32_16x16x32_bf16(afr, wreg[k * 8 + hf * 4 + g], a4[g], 0, 0, 0);
            }
#pragma unroll
            for (int k = 6; k < 8; ++k) {
                bf16x8 afr = AFRAG(hr, k);
#pragma unroll
                for (int g = 0; g < 4; ++g) {
                    bf16x8 w = wldsv[((k - 6) * 64 + wid * 8 + hf * 4 + g) * 64 + lane];
                    a4[g] = __builtin_amdgcn_mfma_f32_16x16x32_bf16(afr, w, a4[g], 0, 0, 0);
                }
            }
            if (lg < 2) {
                const int hcol = wid * 32 + hf * 16 + lc;
#pragma unroll
                for (int r = 0; r < 4; ++r) {
                    const int row = lg * 4 + r;
                    float gi = a4[0][r] + b1v[hf][0];
                    float gj = a4[1][r] + b1v[hf][1];
                    float gf = a4[2][r] + b1v[hf][2];
                    float go = a4[3][r] + b1v[hf][3];
                    float cn = c1[hf][r] * sigf(gf + 1.0f) + sigf(gi) * tanhf2(gj);
                    float h  = tanhf2(cn) * sigf(go);
                    c1[hf][r] = cn;
                    unsigned short hb = f2bf(h);
                    hw[HSWZ(row, hcol)] = *(bf16*)&hb;
                    h1c[((size_t)(b0 + row) * TC + (t - t0)) * 256 + hcol] = hb;
                }
            }
        }
        __syncthreads();
    }
    // persist c1 state for next chunk
    if (t1 < T_SZ && lg < 2) {
#pragma unroll
        for (int hf = 0; hf < 2; ++hf)
#pragma unroll
            for (int r = 0; r < 4; ++r)
                c1g[(size_t)(b0 + lg * 4 + r) * 256 + wid * 32 + hf * 16 + lc] = c1[hf][r];
    }
}

// ===================== kernel G: gxc = h1c @ W2x + b2 (time chunk) =====================
// gxc[bblk][dt][nt][lc][rb] bf16 ; M-tile = 8 rows x 2 t  (m = row*2+dtp)
__global__ __launch_bounds__(NTHR) __attribute__((amdgpu_waves_per_eu(2, 2)))
void gx_gemm(const unsigned short* __restrict__ h1c, const bf16x8* __restrict__ wpG,
             const float* __restrict__ b2, unsigned short* __restrict__ gxc, int TC)
{
    __shared__ __align__(16) bf16 wlds[2 * 4096 * 8];     // 128 KB
    __shared__ __align__(16) bf16 hbuf[16 * 256];         // 8 KB

    const int tid  = threadIdx.x;
    const int lane = tid & 63;
    const int wid  = tid >> 6;
    const int lc   = lane & 15;
    const int lg   = lane >> 4;
    const int bblk = blockIdx.x;

    {
        bf16x8* wv = (bf16x8*)wlds;
        for (int i = tid; i < 2 * 4096; i += NTHR) wv[i] = wpG[6 * 4096 + i];
    }
    bf16x8 wreg[48];
#pragma unroll
    for (int k = 0; k < 6; ++k)
#pragma unroll
        for (int j = 0; j < 8; ++j)
            wreg[k * 8 + j] = wpG[(k * 64 + wid * 8 + j) * 64 + lane];

    float b2v[8];
#pragma unroll
    for (int j = 0; j < 8; ++j)
        b2v[j] = b2[(j & 3) * 256 + wid * 32 + ((j >> 2) & 1) * 16 + lc];

    const f32x4 zf = {0.f, 0.f, 0.f, 0.f};
    const bf16x8* wldsv = (const bf16x8*)wlds;
    const int m    = tid >> 5;
    const int col0 = (tid & 31) * 8;
    const int np   = TC >> 1;

    bf16x8 sreg = *(const bf16x8*)&h1c[((size_t)(bblk * 8 + (m >> 1)) * TC + (m & 1)) * 256 + col0];

    for (int tt = 0; tt < np; ++tt) {
        __syncthreads();
        *(bf16x8*)&hbuf[m * 256 + ((((tid & 31) + 2 * m) & 31) << 3)] = sreg;
        __syncthreads();
        if (tt + 1 < np)
            sreg = *(const bf16x8*)&h1c[((size_t)(bblk * 8 + (m >> 1)) * TC + (tt + 1) * 2 + (m & 1)) * 256 + col0];

        f32x4 acc[8];
#pragma unroll
        for (int j = 0; j < 8; ++j) acc[j] = zf;
#pragma unroll
        for (int k = 0; k < 8; ++k) {
            bf16x8 afr = AFRAG(hbuf, k);
#pragma unroll
            for (int j = 0; j < 8; ++j) {
                bf16x8 w = (k < 6) ? wreg[k * 8 + j]
                                   : wldsv[((k - 6) * 64 + wid * 8 + j) * 64 + lane];
                acc[j] = __builtin_amdgcn_mfma_f32_16x16x32_bf16(afr, w, acc[j], 0, 0, 0);
            }
        }
#pragma unroll
        for (int j = 0; j < 8; ++j) {
            const int nt = wid * 8 + j;
#pragma unroll
            for (int r = 0; r < 4; ++r) {
                size_t addr = ((((size_t)bblk * TC + tt * 2 + (r & 1)) * 64 + nt) * 16 + lc) * 8
                              + 2 * lg + (r >> 1);
                gxc[addr] = f2bf(acc[j][r] + b2v[j]);
            }
        }
    }
}

// ===================== kernel B: layer-2 recurrence (+ loss on final chunk) =====================
__global__ __launch_bounds__(NTHR) __attribute__((amdgpu_waves_per_eu(2, 2)))
void lstm_l2(const bf16x8* __restrict__ wpB, const unsigned short* __restrict__ gxc,
             const int* __restrict__ labels,
             const float* __restrict__ Wd, const float* __restrict__ bd,
             float* __restrict__ out, float* __restrict__ c2g,
             unsigned short* __restrict__ h2p, int t0, int TC)
{
    __shared__ __align__(16) bf16 wlds[2 * 4096 * 8];     // 128 KB
    __shared__ __align__(16) bf16 h2s[2][16 * 256];       // 16 KB
    __shared__ float logitb[8][VOCABN + 1];
    __shared__ float lossb[8];

    const int tid  = threadIdx.x;
    const int lane = tid & 63;
    const int wid  = tid >> 6;
    const int lc   = lane & 15;
    const int lg   = lane >> 4;
    const int bblk = blockIdx.x;
    const int b0   = bblk * 8;
    const int t1   = t0 + TC;

    for (int i = tid; i < 2 * 16 * 256; i += NTHR) h2s[0][i] = (bf16)0.0f;
    {
        bf16x8* wv = (bf16x8*)wlds;
        for (int i = tid; i < 2 * 4096; i += NTHR) wv[i] = wpB[6 * 4096 + i];
    }
    float c2[2][4] = {{0.f,0.f,0.f,0.f},{0.f,0.f,0.f,0.f}};
    if (t0 > 0) {
        __syncthreads();
        for (int i = tid; i < 256; i += NTHR) {
            int row = i >> 5, col0 = (i & 31) << 3;
            bf16x8 v = *(const bf16x8*)&h2p[(size_t)(b0 + row) * 256 + col0];
            *(bf16x8*)&h2s[0][HSWZ(row, col0)] = v;
        }
        if (lg < 2) {
#pragma unroll
            for (int hf = 0; hf < 2; ++hf)
#pragma unroll
                for (int r = 0; r < 4; ++r)
                    c2[hf][r] = c2g[(size_t)(b0 + lg * 4 + r) * 256 + wid * 32 + hf * 16 + lc];
        }
    }
    __syncthreads();

    bf16x8 wreg[48];
#pragma unroll
    for (int k = 0; k < 6; ++k)
#pragma unroll
        for (int j = 0; j < 8; ++j)
            wreg[k * 8 + j] = wpB[(k * 64 + wid * 8 + j) * 64 + lane];

    const f32x4 zf = {0.f, 0.f, 0.f, 0.f};
    const bf16x8* wldsv = (const bf16x8*)wlds;

    for (int t = t0; t < t1; ++t) {
        const int rb_ = t & 1;
        const bf16* hr = h2s[rb_];
        bf16* hw = h2s[rb_ ^ 1];

        u16x4 gxv[2][4];
        if (lg < 2) {
#pragma unroll
            for (int hf = 0; hf < 2; ++hf)
#pragma unroll
                for (int g = 0; g < 4; ++g) {
                    const int nt = wid * 8 + hf * 4 + g;
                    size_t addr = ((((size_t)bblk * TC + (t - t0)) * 64 + nt) * 16 + lc) * 8 + 4 * lg;
                    gxv[hf][g] = *(const u16x4*)(gxc + addr);
                }
        }

#pragma unroll
        for (int hf = 0; hf < 2; ++hf) {
            f32x4 a4[4];
#pragma unroll
            for (int g = 0; g < 4; ++g) a4[g] = zf;
#pragma unroll
            for (int k = 0; k < 6; ++k) {
                bf16x8 afr = AFRAG(hr, k);
#pragma unroll
                for (int g = 0; g < 4; ++g)
                    a4[g] = __builtin_amdgcn_mfma_f32_16x16x32_bf16(afr, wreg[k * 8 + hf * 4 + g], a4[g], 0, 0, 0);
            }
#pragma unroll
            for (int k = 6; k < 8; ++k) {
                bf16x8 afr = AFRAG(hr, k);
#pragma unroll
                for (int g = 0; g < 4; ++g) {
                    bf16x8 w = wldsv[((k - 6) * 64 + wid * 8 + hf * 4 + g) * 64 + lane];
                    a4[g] = __builtin_amdgcn_mfma_f32_16x16x32_bf16(afr, w, a4[g], 0, 0, 0);
                }
            }
            if (lg < 2) {
                const int hcol = wid * 32 + hf * 16 + lc;
#pragma unroll
                for (int r = 0; r < 4; ++r) {
                    const int row = lg * 4 + r;
                    float gi = a4[0][r] + bf2f(gxv[hf][0][r]);
                    float gj = a4[1][r] + bf2f(gxv[hf][1][r]);
                    float gf = a4[2][r] + bf2f(gxv[hf][2][r]);
                    float go = a4[3][r] + bf2f(gxv[hf][3][r]);
                    float cn = c2[hf][r] * sigf(gf + 1.0f) + sigf(gi) * tanhf2(gj);
                    float h  = tanhf2(cn) * sigf(go);
                    c2[hf][r] = cn;
                    unsigned short hb = f2bf(h);
                    hw[HSWZ(row, hcol)] = *(bf16*)&hb;
                }
            }
        }
        __syncthreads();
    }

    if (t1 < T_SZ) {
        // persist state (final h2 of this chunk is in h2s[0] since t1 even)
        if (lg < 2) {
#pragma unroll
            for (int hf = 0; hf < 2; ++hf)
#pragma unroll
                for (int r = 0; r < 4; ++r)
                    c2g[(size_t)(b0 + lg * 4 + r) * 256 + wid * 32 + hf * 16 + lc] = c2[hf][r];
        }
        for (int i = tid; i < 256; i += NTHR) {
            int row = i >> 5, col0 = (i & 31) << 3;
            bf16x8 v = *(const bf16x8*)&h2s[0][HSWZ(row, col0)];
            *(bf16x8*)&h2p[(size_t)(b0 + row) * 256 + col0] = v;
        }
        return;
    }

    // ---- loss epilogue (final chunk): final h2 in h2s[0] ----
    const bf16* h2fin = h2s[0];
    for (int pp = tid; pp < 8 * VOCABN; pp += NTHR) {
        int row = pp / VOCABN, v = pp - row * VOCABN;
        float s = bd[v];
        for (int k = 0; k < HID; ++k)
            s += (float)h2fin[HSWZ(row, k)] * Wd[k * VOCABN + v];
        logitb[row][v] = s;
    }
    __syncthreads();
    if (tid < 8) {
        float mx = -1e30f;
        for (int v = 0; v < VOCABN; ++v) mx = fmaxf(mx, logitb[tid][v]);
        float s = 0.f;
        for (int v = 0; v < VOCABN; ++v) s += __expf(logitb[tid][v] - mx);
        int lab = labels[b0 + tid];
        lossb[tid] = mx + __logf(s) - logitb[tid][lab];
    }
    __syncthreads();
    if (tid == 0) {
        float s = 0.f;
#pragma unroll
        for (int r = 0; r < 8; ++r) s += lossb[r];
        atomicAdd(out, s * (1.0f / (float)B_SZ));
    }
}

// ===================== R5 fallback (verbatim, passed @5.16ms) =====================
#define NCH_R5 24
#define CHE_R5 32768
#define TILE_R5 16
#define NBLK_R5 (B_SZ / TILE_R5)

__global__ void prep_w_r5(const float* __restrict__ W1, const float* __restrict__ W2,
                          unsigned short* __restrict__ wp) {
    int idx = blockIdx.x * blockDim.x + threadIdx.x;
    if (idx >= 25 * 64 * 64) return;
    int lane = idx & 63, nt = (idx >> 6) & 63, k = idx >> 12;
    int scol = (nt << 4) + (lane & 15);
    int lg = lane >> 4;
#pragma unroll
    for (int e = 0; e < 8; ++e) {
        float val;
        if (k < 8)       val = W1[(EMBN + k * 32 + lg * 8 + e) * G4 + scol];
        else if (k < 24) val = W2[((k - 8) * 32 + lg * 8 + e) * G4 + scol];
        else             val = (lg == 0) ? W1[e * G4 + scol] : 0.0f;
        wp[idx * 8 + e] = f2bf(val);
    }
}

#define WAITVM_R5(N) do { asm volatile("s_waitcnt vmcnt(" #N ")" ::: "memory"); \
                       __builtin_amdgcn_sched_barrier(0); } while (0)
#define WAITLG_R5    do { asm volatile("s_waitcnt lgkmcnt(0)" ::: "memory");    \
                       __builtin_amdgcn_sched_barrier(0); } while (0)
#define BAR_R5       do { __builtin_amdgcn_s_barrier();                         \
                       __builtin_amdgcn_sched_barrier(0); } while (0)

#define STAGE_R5(kk, bb) do {                                                   \
    const bf16* gs_ = wp + (size_t)(kk) * CHE_R5;                               \
    _Pragma("unroll")                                                           \
    for (int j_ = 0; j_ < 8; ++j_) {                                            \
        const int f_ = j_ * 512 + wid * 64;                                     \
        __builtin_amdgcn_global_load_lds(                                       \
            (const __attribute__((address_space(1))) void*)(gs_ + (size_t)(f_ + lane) * 8), \
            (__attribute__((address_space(3))) void*)(&wbuf[bb][0] + (size_t)f_ * 8),       \
            16, 0, 0);                                                          \
    }                                                                           \
} while (0)

#define CHUNK_R5(c, HSRC, KIDX, EXTRA) do {                                     \
    WAITVM_R5(8); BAR_R5;                                                       \
    {                                                                           \
        const bf16* wb_ = wbuf[(c) & 1];                                        \
        bf16x8 afr_ = AFRAG(HSRC, KIDX);                                        \
        _Pragma("unroll")                                                       \
        for (int j_ = 0; j_ < 8; ++j_) {                                        \
            const int nt_ = (j_ >> 1) * 16 + 2 * wid + (j_ & 1);                \
            bf16x8 w_ = *(const bf16x8*)&wb_[(nt_ * 64 + lane) * 8];            \
            acc[j_ >> 1][j_ & 1] = __builtin_amdgcn_mfma_f32_16x16x32_bf16(     \
                afr_, w_, acc[j_ >> 1][j_ & 1], 0, 0, 0);                       \
        }                                                                       \
        EXTRA;                                                                  \
    }                                                                           \
    WAITLG_R5; BAR_R5;                                                          \
    STAGE_R5(((c) + 2) % NCH_R5, ((c) + 2) & 1);                                \
} while (0)

#define XMFMA_R5 do {                                                           \
    const int tok_ = toks[lc * T_SZ + t];                                       \
    bf16x8 ax_;                                                                 \
    _Pragma("unroll") for (int e_ = 0; e_ < 8; ++e_) ax_[e_] = (bf16)0.0f;      \
    if (lg == 0) ax_ = *(const bf16x8*)&embL[tok_ * 8];                         \
    _Pragma("unroll")                                                           \
    for (int j_ = 0; j_ < 8; ++j_)                                              \
        acc[j_ >> 1][j_ & 1] = __builtin_amdgcn_mfma_f32_16x16x32_bf16(         \
            ax_, w1x[j_], acc[j_ >> 1][j_ & 1], 0, 0, 0);                       \
} while (0)

#define ACCZ_R5() do { _Pragma("unroll") for (int g_ = 0; g_ < 4; ++g_) {       \
    acc[g_][0] = zf; acc[g_][1] = zf; } } while (0)

__global__ __launch_bounds__(NTHR, 2)
void lstm_fused_r5(const int* __restrict__ feat, const int* __restrict__ labels,
                const bf16* __restrict__ wp,
                const float* __restrict__ b1, const float* __restrict__ b2,
                const float* __restrict__ emb,
                const float* __restrict__ Wd, const float* __restrict__ bd,
                float* __restrict__ out)
{
    __shared__ __align__(16) bf16  wbuf[2][CHE_R5];
    __shared__ __align__(16) bf16  h1s[TILE_R5 * 256];
    __shared__ __align__(16) bf16  h2s[TILE_R5 * 256];
    __shared__ __align__(16) bf16  embL[VOCABN * 8];
    __shared__ int   toks[TILE_R5 * T_SZ];
    __shared__ float logitb[TILE_R5][VOCABN + 1];
    __shared__ float lossb[TILE_R5];

    const int tid  = threadIdx.x;
    const int lane = tid & 63;
    const int wid  = tid >> 6;
    const int lc   = lane & 15;
    const int lg   = lane >> 4;
    const int b0   = blockIdx.x * TILE_R5;

    for (int i = tid; i < TILE_R5 * 256; i += NTHR) { h1s[i] = (bf16)0.0f; h2s[i] = (bf16)0.0f; }
    for (int i = tid; i < TILE_R5 * T_SZ; i += NTHR) {
        int r = i / T_SZ, t = i - r * T_SZ;
        toks[r * T_SZ + t] = feat[(b0 + r) * T_SZ + t];
    }
    for (int i = tid; i < VOCABN * 8; i += NTHR) ((unsigned short*)embL)[i] = f2bf(emb[i]);
    __syncthreads();

    bf16x8 w1x[8];
#pragma unroll
    for (int j = 0; j < 8; ++j) {
        const int nt = (j >> 1) * 16 + 2 * wid + (j & 1);
        w1x[j] = *(const bf16x8*)&wp[((size_t)24 * 64 * 64 + nt * 64 + lane) * 8];
    }
    float b1v[4][2], b2v[4][2];
#pragma unroll
    for (int g = 0; g < 4; ++g)
#pragma unroll
        for (int d = 0; d < 2; ++d) {
            b1v[g][d] = b1[g * 256 + (2 * wid + d) * 16 + lc];
            b2v[g][d] = b2[g * 256 + (2 * wid + d) * 16 + lc];
        }

    const f32x4 zf = {0.f, 0.f, 0.f, 0.f};
    f32x4 acc[4][2];
    float c1s[2][4] = {{0.f,0.f,0.f,0.f},{0.f,0.f,0.f,0.f}};
    float c2s[2][4] = {{0.f,0.f,0.f,0.f},{0.f,0.f,0.f,0.f}};

    STAGE_R5(0, 0);
    STAGE_R5(1, 1);

    for (int t = 0; t < T_SZ; ++t) {
        ACCZ_R5();
        CHUNK_R5(0, h1s, 0, XMFMA_R5);
        CHUNK_R5(1, h1s, 1, );
        CHUNK_R5(2, h1s, 2, );
        CHUNK_R5(3, h1s, 3, );
        CHUNK_R5(4, h1s, 4, );
        CHUNK_R5(5, h1s, 5, );
        CHUNK_R5(6, h1s, 6, );
        CHUNK_R5(7, h1s, 7, );
#pragma unroll
        for (int d = 0; d < 2; ++d) {
            const int hcol = (2 * wid + d) * 16 + lc;
#pragma unroll
            for (int rr = 0; rr < 4; ++rr) {
                const int row = lg * 4 + rr;
                float gi = acc[0][d][rr] + b1v[0][d];
                float gj = acc[1][d][rr] + b1v[1][d];
                float gf = acc[2][d][rr] + b1v[2][d];
                float go = acc[3][d][rr] + b1v[3][d];
                float cn = c1s[d][rr] * sigf(gf + 1.0f) + sigf(gi) * tanhf2(gj);
                float h  = tanhf2(cn) * sigf(go);
                c1s[d][rr] = cn;
                h1s[HSWZ(row, hcol)] = (bf16)h;
            }
        }
        ACCZ_R5();
        CHUNK_R5(8,  h1s, 0, );
        CHUNK_R5(9,  h1s, 1, );
        CHUNK_R5(10, h1s, 2, );
        CHUNK_R5(11, h1s, 3, );
        CHUNK_R5(12, h1s, 4, );
        CHUNK_R5(13, h1s, 5, );
        CHUNK_R5(14, h1s, 6, );
        CHUNK_R5(15, h1s, 7, );
        CHUNK_R5(16, h2s, 0, );
        CHUNK_R5(17, h2s, 1, );
        CHUNK_R5(18, h2s, 2, );
        CHUNK_R5(19, h2s, 3, );
        CHUNK_R5(20, h2s, 4, );
        CHUNK_R5(21, h2s, 5, );
        CHUNK_R5(22, h2s, 6, );
        CHUNK_R5(23, h2s, 7, );
#pragma unroll
        for (int d = 0; d < 2; ++d) {
            const int hcol = (2 * wid + d) * 16 + lc;
#pragma unroll
            for (int rr = 0; rr < 4; ++rr) {
                const int row = lg * 4 + rr;
                float gi = acc[0][d][rr] + b2v[0][d];
                float gj = acc[1][d][rr] + b2v[1][d];
                float gf = acc[2][d][rr] + b2v[2][d];
                float go = acc[3][d][rr] + b2v[3][d];
                float cn = c2s[d][rr] * sigf(gf + 1.0f) + sigf(gi) * tanhf2(gj);
                float h  = tanhf2(cn) * sigf(go);
                c2s[d][rr] = cn;
                h2s[HSWZ(row, hcol)] = (bf16)h;
            }
        }
    }
    __syncthreads();

    for (int pp = tid; pp < TILE_R5 * VOCABN; pp += NTHR) {
        int row = pp / VOCABN, v = pp - row * VOCABN;
        float s = bd[v];
        for (int k = 0; k < HID; ++k)
            s += (float)h2s[HSWZ(row, k)] * Wd[k * VOCABN + v];
        logitb[row][v] = s;
    }
    __syncthreads();
    if (tid < TILE_R5) {
        const int row = tid;
        float m = -1e30f;
        for (int v = 0; v < VOCABN; ++v) m = fmaxf(m, logitb[row][v]);
        float s = 0.f;
        for (int v = 0; v < VOCABN; ++v) s += __expf(logitb[row][v] - m);
        int lab = labels[b0 + row];
        lossb[row] = m + __logf(s) - logitb[row][lab];
    }
    __syncthreads();
    if (tid == 0) {
        float s = 0.f;
#pragma unroll
        for (int rr = 0; rr < TILE_R5; ++rr) s += lossb[rr];
        atomicAdd(out, s * (1.0f / (float)B_SZ));
    }
}

// ===================== launch =====================
extern "C" void kernel_launch(void* const* d_in, const int* in_sizes, int n_in,
                              void* d_out, int out_size, void* d_ws, size_t ws_size,
                              hipStream_t stream)
{
    (void)in_sizes; (void)n_in; (void)out_size;
    const int*   feat   = (const int*)d_in[0];
    const int*   labels = (const int*)d_in[1];
    const float* emb    = (const float*)d_in[2];
    const float* W1     = (const float*)d_in[3];
    const float* b1     = (const float*)d_in[4];
    const float* W2     = (const float*)d_in[5];
    const float* b2     = (const float*)d_in[6];
    const float* Wd     = (const float*)d_in[7];
    const float* bd     = (const float*)d_in[8];
    float* out = (float*)d_out;
    char* ws = (char*)d_ws;

    (void)hipMemsetAsync(d_out, 0, sizeof(float), stream);

    // pick largest even time-chunk that fits
    int TC = 0;
    {
        const int tcs[7] = {40, 20, 16, 10, 8, 4, 2};
        for (int i = 0; i < 7; ++i)
            if (FIXED_WS + (size_t)tcs[i] * PER_TC <= ws_size) { TC = tcs[i]; break; }
    }

    if (TC > 0) {
        unsigned short* wpA  = (unsigned short*)(ws + WPA_OFF);
        unsigned short* wpG  = (unsigned short*)(ws + WPG_OFF);
        unsigned short* wpB  = (unsigned short*)(ws + WPB_OFF);
        unsigned short* w1xg = (unsigned short*)(ws + W1X_OFF);
        float*          c1g  = (float*)(ws + C1G_OFF);
        float*          c2g  = (float*)(ws + C2G_OFF);
        unsigned short* h2p  = (unsigned short*)(ws + H2P_OFF);
        unsigned short* h1c  = (unsigned short*)(ws + H1C_OFF);
        unsigned short* gxc  = (unsigned short*)(ws + H1C_OFF + (size_t)TC * 1048576ull);

        prep_all<<<(3 * 8 * 64 * 64 + 64 * 64 + 255) / 256, 256, 0, stream>>>(
            W1, W2, wpA, wpG, wpB, w1xg);
        for (int t0 = 0; t0 < T_SZ; t0 += TC) {
            lstm_l1<<<256, NTHR, 0, stream>>>(feat, (const bf16x8*)wpA, (const bf16x8*)w1xg,
                                              emb, b1, h1c, c1g, t0, TC);
            gx_gemm<<<256, NTHR, 0, stream>>>(h1c, (const bf16x8*)wpG, b2, gxc, TC);
            lstm_l2<<<256, NTHR, 0, stream>>>((const bf16x8*)wpB, gxc, labels, Wd, bd,
                                              out, c2g, h2p, t0, TC);
        }
    } else {
        bf16* wp = (bf16*)d_ws;
        prep_w_r5<<<(25 * 64 * 64 + 255) / 256, 256, 0, stream>>>(W1, W2, (unsigned short*)wp);
        lstm_fused_r5<<<NBLK_R5, NTHR, 0, stream>>>(feat, labels, wp, b1, b2, emb, Wd, bd, out);
    }
}

// Round 12
// 792.747 us; speedup vs baseline: 2.5299x; 2.5299x over previous
//
#include <hip/hip_runtime.h>
#include <cstdint>

#define B_SZ   2048
#define T_SZ   80
#define VOCABN 80
#define EMBN   8
#define HID    256
#define G4     1024
#define NTHR   512
#define HP     272        // int8 h-tile row pitch (16B-aligned, odd 16B blocks)

typedef __bf16 bf16;
typedef __attribute__((ext_vector_type(4))) int    i32x4;
typedef __attribute__((ext_vector_type(4))) float  f32x4;
typedef __attribute__((ext_vector_type(4))) unsigned short u16x4;

__device__ __forceinline__ float sigf(float x)   { return 1.0f / (1.0f + __expf(-x)); }
__device__ __forceinline__ float tanhf2(float x) { return 1.0f - 2.0f / (__expf(2.0f * x) + 1.0f); }

__device__ __forceinline__ unsigned short f2bf(float f) {
    union { float f; unsigned int u; } v; v.f = f;
    unsigned int u = v.u;
    return (unsigned short)((u + 0x7FFFu + ((u >> 16) & 1u)) >> 16);
}
__device__ __forceinline__ float bf2f(unsigned short h) {
    union { unsigned int u; float f; } v; v.u = ((unsigned int)h) << 16;
    return v.f;
}
__device__ __forceinline__ signed char q8(float h) {
    int q = (int)rintf(h * 127.0f);
    q = q > 127 ? 127 : (q < -127 ? -127 : q);
    return (signed char)q;
}

// ===================== ws layout =====================
// wp8: 3 matrices (W1h, W2x, W2h) x [ks(4)][nt(64)][lane(64)][16B] int8
#define WP8_OFF  0ull                       // 786432 B
#define EG2_OFF  786432ull                  // 327680 B  eg2[tok][256][4] f32 (emb@W1x + b1)
#define SW_OFF   1114112ull                 // 12288 B   sw[3][1024] f32 column scales
#define C1G_OFF  1126400ull                 // 2 MB  c1 f32 [2048][256]
#define C2G_OFF  3223552ull                 // 2 MB  c2 f32
#define H2P_OFF  5320704ull                 // 512 KB h2 int8 [2048][256]
#define H1C_OFF  5844992ull                 // TC*512KB h1c int8 [b][dt][256]
#define FIXED_WS 5844992ull
#define PER_TC   4718592ull                 // 512KB h1c + 4MB gxc per t

// ===================== prep kernels =====================
__global__ void prep_scale(const float* __restrict__ W1, const float* __restrict__ W2,
                           float* __restrict__ sw) {
    int idx = blockIdx.x * blockDim.x + threadIdx.x;
    if (idx >= 3 * 1024) return;
    int s = idx >> 10, c = idx & 1023;
    float m = 0.0f;
    for (int r = 0; r < 256; ++r) {
        float v = (s == 0) ? W1[(EMBN + r) * G4 + c]
                : (s == 1) ? W2[r * G4 + c]
                           : W2[(256 + r) * G4 + c];
        m = fmaxf(m, fabsf(v));
    }
    sw[idx] = m * (1.0f / 127.0f) + 1e-20f;
}

// nt = w*8 + hf*4 + g ; scol = (nt&3)*256 + (nt>>3)*32 + ((nt>>2)&1)*16 + lc
__global__ void prep_pack(const float* __restrict__ W1, const float* __restrict__ W2,
                          const float* __restrict__ sw, signed char* __restrict__ wp8) {
    int idx = blockIdx.x * blockDim.x + threadIdx.x;
    if (idx >= 3 * 4 * 64 * 64) return;
    int lane = idx & 63, nt = (idx >> 6) & 63, ks = (idx >> 12) & 3, s = idx >> 14;
    int lc = lane & 15, lg = lane >> 4;
    int scol = (nt & 3) * 256 + (nt >> 3) * 32 + ((nt >> 2) & 1) * 16 + lc;
    float sc = 1.0f / sw[s * 1024 + scol];
#pragma unroll
    for (int e = 0; e < 16; ++e) {
        int row = ks * 64 + lg * 16 + e;
        float v = (s == 0) ? W1[(EMBN + row) * G4 + scol]
                : (s == 1) ? W2[row * G4 + scol]
                           : W2[(256 + row) * G4 + scol];
        int q = (int)rintf(v * sc);
        q = q > 127 ? 127 : (q < -127 ? -127 : q);
        wp8[(size_t)idx * 16 + e] = (signed char)q;
    }
}

// eg2[tok][hcol][g] = emb[tok]@W1x[:, g*256+hcol] + b1[g*256+hcol]   (f32x4 per (tok,hcol))
__global__ void prep_eg2(const float* __restrict__ emb, const float* __restrict__ W1,
                         const float* __restrict__ b1, float* __restrict__ eg2) {
    int idx = blockIdx.x * blockDim.x + threadIdx.x;
    if (idx >= VOCABN * 256) return;
    int v = idx >> 8, h = idx & 255;
#pragma unroll
    for (int g = 0; g < 4; ++g) {
        int c = g * 256 + h;
        float s = b1[c];
#pragma unroll
        for (int e = 0; e < EMBN; ++e) s += emb[v * EMBN + e] * W1[e * G4 + c];
        eg2[(size_t)idx * 4 + g] = s;
    }
}

// ===================== kernel A: layer-1 recurrence (int8, time chunk) =====================
__global__ __launch_bounds__(NTHR, 2)
void lstm_l1(const int* __restrict__ feat,
             const signed char* __restrict__ wp8A, const float* __restrict__ swA,
             const float* __restrict__ eg2,
             signed char* __restrict__ h1c, float* __restrict__ c1g,
             int t0, int TC)
{
    __shared__ __align__(16) signed char wlds[2][64][1024];   // ks 2,3: 128 KB
    __shared__ __align__(16) signed char h1s[2][16 * HP];     // 8.5 KB (rows 8..15 stay 0)
    __shared__ unsigned char toks8[8 * T_SZ];

    const int tid  = threadIdx.x;
    const int lane = tid & 63;
    const int wid  = tid >> 6;
    const int lc   = lane & 15;
    const int lg   = lane >> 4;
    const int bblk = blockIdx.x;
    const int b0   = bblk * 8;
    const int t1   = t0 + TC;

    for (int i = tid; i < 2 * 16 * HP; i += NTHR) h1s[0][i] = 0;
    for (int i = tid; i < 8 * T_SZ; i += NTHR) {
        int r = i / T_SZ, t = i - r * T_SZ;
        toks8[i] = (unsigned char)feat[(b0 + r) * T_SZ + t];
    }
    {   // wlds <- slices ks=2,3 (verbatim fragment order)
        for (int i = tid; i < 2 * 64 * 64; i += NTHR)
            *(i32x4*)&wlds[0][0][(size_t)i * 16] =
                *(const i32x4*)&wp8A[(size_t)(2 * 64 * 64 + i) * 16];
    }
    float c1[2][4] = {{0.f,0.f,0.f,0.f},{0.f,0.f,0.f,0.f}};
    if (t0 > 0) {
        __syncthreads();   // zero-fill complete before carry overwrite
        for (int i = tid; i < 8 * 256; i += NTHR) {
            int row = i >> 8, col = i & 255;
            h1s[0][row * HP + col] = h1c[((size_t)(b0 + row) * TC + (TC - 1)) * 256 + col];
        }
        if (lg < 2) {
#pragma unroll
            for (int hf = 0; hf < 2; ++hf)
#pragma unroll
                for (int r = 0; r < 4; ++r)
                    c1[hf][r] = c1g[(size_t)(b0 + lg * 4 + r) * 256 + wid * 32 + hf * 16 + lc];
        }
    }
    __syncthreads();

    // registers: slices ks=0,1 for this wave's 8 nt tiles (64 VGPR)
    i32x4 wreg[16];
#pragma unroll
    for (int ks = 0; ks < 2; ++ks)
#pragma unroll
        for (int j = 0; j < 8; ++j)
            wreg[ks * 8 + j] = *(const i32x4*)&wp8A[(size_t)((ks * 64 + wid * 8 + j) * 64 + lane) * 16];

    float ss[2][4];
#pragma unroll
    for (int hf = 0; hf < 2; ++hf)
#pragma unroll
        for (int g = 0; g < 4; ++g)
            ss[hf][g] = swA[g * 256 + wid * 32 + hf * 16 + lc] * (1.0f / 127.0f);

    const i32x4 zi = {0, 0, 0, 0};

    for (int t = t0; t < t1; ++t) {
        const int rb_ = t & 1;
        const signed char* hr = h1s[rb_];
        signed char* hw = h1s[rb_ ^ 1];

#pragma unroll
        for (int hf = 0; hf < 2; ++hf) {
            i32x4 ia[4];
#pragma unroll
            for (int g = 0; g < 4; ++g) ia[g] = zi;
#pragma unroll
            for (int ks = 0; ks < 4; ++ks) {
                i32x4 afr = *(const i32x4*)&hr[lc * HP + ks * 64 + lg * 16];
#pragma unroll
                for (int g = 0; g < 4; ++g) {
                    i32x4 w = (ks < 2) ? wreg[ks * 8 + hf * 4 + g]
                            : *(const i32x4*)&wlds[ks - 2][wid * 8 + hf * 4 + g][(size_t)lane * 16];
                    ia[g] = __builtin_amdgcn_mfma_i32_16x16x64_i8(afr, w, ia[g], 0, 0, 0);
                }
            }
            if (lg < 2) {
                const int hcol = wid * 32 + hf * 16 + lc;
#pragma unroll
                for (int r = 0; r < 4; ++r) {
                    const int row = lg * 4 + r;
                    const int tok = toks8[row * T_SZ + t];
                    f32x4 e4 = *(const f32x4*)&eg2[((size_t)tok * 256 + hcol) * 4];
                    float gi = ss[hf][0] * (float)ia[0][r] + e4[0];
                    float gj = ss[hf][1] * (float)ia[1][r] + e4[1];
                    float gf = ss[hf][2] * (float)ia[2][r] + e4[2];
                    float go = ss[hf][3] * (float)ia[3][r] + e4[3];
                    float cn = c1[hf][r] * sigf(gf + 1.0f) + sigf(gi) * tanhf2(gj);
                    float h  = tanhf2(cn) * sigf(go);
                    c1[hf][r] = cn;
                    signed char qv = q8(h);
                    hw[row * HP + hcol] = qv;
                    h1c[((size_t)(b0 + row) * TC + (t - t0)) * 256 + hcol] = qv;
                }
            }
        }
        __syncthreads();
    }
    if (t1 < T_SZ && lg < 2) {
#pragma unroll
        for (int hf = 0; hf < 2; ++hf)
#pragma unroll
            for (int r = 0; r < 4; ++r)
                c1g[(size_t)(b0 + lg * 4 + r) * 256 + wid * 32 + hf * 16 + lc] = c1[hf][r];
    }
}

// ===================== kernel G: gxc = h1c @ W2x + b2 (int8, time chunk) =====================
__global__ __launch_bounds__(NTHR, 2)
void gx_gemm(const signed char* __restrict__ h1c,
             const signed char* __restrict__ wp8G, const float* __restrict__ swG,
             const float* __restrict__ b2, unsigned short* __restrict__ gxc, int TC)
{
    __shared__ __align__(16) signed char wlds[2][64][1024];   // 128 KB
    __shared__ __align__(16) signed char hbuf[16 * HP];       // 4.3 KB

    const int tid  = threadIdx.x;
    const int lane = tid & 63;
    const int wid  = tid >> 6;
    const int lc   = lane & 15;
    const int lg   = lane >> 4;
    const int bblk = blockIdx.x;

    for (int i = tid; i < 2 * 64 * 64; i += NTHR)
        *(i32x4*)&wlds[0][0][(size_t)i * 16] =
            *(const i32x4*)&wp8G[(size_t)(2 * 64 * 64 + i) * 16];

    i32x4 wreg[16];
#pragma unroll
    for (int ks = 0; ks < 2; ++ks)
#pragma unroll
        for (int j = 0; j < 8; ++j)
            wreg[ks * 8 + j] = *(const i32x4*)&wp8G[(size_t)((ks * 64 + wid * 8 + j) * 64 + lane) * 16];

    float ssg[8], b2v[8];
#pragma unroll
    for (int j = 0; j < 8; ++j) {
        int scol = (j & 3) * 256 + wid * 32 + ((j >> 2) & 1) * 16 + lc;
        ssg[j] = swG[scol] * (1.0f / 127.0f);
        b2v[j] = b2[scol];
    }

    const i32x4 zi = {0, 0, 0, 0};
    const int m    = tid >> 5;            // staging row 0..15 (batch m>>1, dt m&1)
    const int col0 = (tid & 31) * 8;
    const int np   = TC >> 1;

    unsigned long long sreg =
        *(const unsigned long long*)&h1c[((size_t)(bblk * 8 + (m >> 1)) * TC + (m & 1)) * 256 + col0];

    for (int tt = 0; tt < np; ++tt) {
        __syncthreads();
        *(unsigned long long*)&hbuf[m * HP + col0] = sreg;
        __syncthreads();
        if (tt + 1 < np)
            sreg = *(const unsigned long long*)
                &h1c[((size_t)(bblk * 8 + (m >> 1)) * TC + (tt + 1) * 2 + (m & 1)) * 256 + col0];

        i32x4 acc[8];
#pragma unroll
        for (int j = 0; j < 8; ++j) acc[j] = zi;
#pragma unroll
        for (int ks = 0; ks < 4; ++ks) {
            i32x4 afr = *(const i32x4*)&hbuf[lc * HP + ks * 64 + lg * 16];
#pragma unroll
            for (int j = 0; j < 8; ++j) {
                i32x4 w = (ks < 2) ? wreg[ks * 8 + j]
                        : *(const i32x4*)&wlds[ks - 2][wid * 8 + j][(size_t)lane * 16];
                acc[j] = __builtin_amdgcn_mfma_i32_16x16x64_i8(afr, w, acc[j], 0, 0, 0);
            }
        }
        // store: row m' = lg*4+r -> batch row = 2lg+(r>>1), dt = r&1 (R10-verbatim map)
#pragma unroll
        for (int j = 0; j < 8; ++j) {
            const int nt = wid * 8 + j;
#pragma unroll
            for (int r = 0; r < 4; ++r) {
                size_t addr = ((((size_t)bblk * TC + tt * 2 + (r & 1)) * 64 + nt) * 16 + lc) * 8
                              + 2 * lg + (r >> 1);
                gxc[addr] = f2bf(ssg[j] * (float)acc[j][r] + b2v[j]);
            }
        }
    }
}

// ===================== kernel B: layer-2 recurrence (+ loss on final chunk) =====================
__global__ __launch_bounds__(NTHR, 2)
void lstm_l2(const signed char* __restrict__ wp8B, const float* __restrict__ swB,
             const unsigned short* __restrict__ gxc,
             const int* __restrict__ labels,
             const float* __restrict__ Wd, const float* __restrict__ bd,
             float* __restrict__ out, float* __restrict__ c2g,
             signed char* __restrict__ h2p, int t0, int TC)
{
    __shared__ __align__(16) signed char wlds[2][64][1024];   // 128 KB
    __shared__ __align__(16) signed char h2s[2][16 * HP];     // 8.5 KB
    __shared__ float logitb[8][VOCABN + 1];
    __shared__ float lossb[8];

    const int tid  = threadIdx.x;
    const int lane = tid & 63;
    const int wid  = tid >> 6;
    const int lc   = lane & 15;
    const int lg   = lane >> 4;
    const int bblk = blockIdx.x;
    const int b0   = bblk * 8;
    const int t1   = t0 + TC;

    for (int i = tid; i < 2 * 16 * HP; i += NTHR) h2s[0][i] = 0;
    for (int i = tid; i < 2 * 64 * 64; i += NTHR)
        *(i32x4*)&wlds[0][0][(size_t)i * 16] =
            *(const i32x4*)&wp8B[(size_t)(2 * 64 * 64 + i) * 16];

    float c2[2][4] = {{0.f,0.f,0.f,0.f},{0.f,0.f,0.f,0.f}};
    if (t0 > 0) {
        __syncthreads();
        for (int i = tid; i < 8 * 256; i += NTHR) {
            int row = i >> 8, col = i & 255;
            h2s[0][row * HP + col] = h2p[(size_t)(b0 + row) * 256 + col];
        }
        if (lg < 2) {
#pragma unroll
            for (int hf = 0; hf < 2; ++hf)
#pragma unroll
                for (int r = 0; r < 4; ++r)
                    c2[hf][r] = c2g[(size_t)(b0 + lg * 4 + r) * 256 + wid * 32 + hf * 16 + lc];
        }
    }
    __syncthreads();

    i32x4 wreg[16];
#pragma unroll
    for (int ks = 0; ks < 2; ++ks)
#pragma unroll
        for (int j = 0; j < 8; ++j)
            wreg[ks * 8 + j] = *(const i32x4*)&wp8B[(size_t)((ks * 64 + wid * 8 + j) * 64 + lane) * 16];

    float ss[2][4];
#pragma unroll
    for (int hf = 0; hf < 2; ++hf)
#pragma unroll
        for (int g = 0; g < 4; ++g)
            ss[hf][g] = swB[g * 256 + wid * 32 + hf * 16 + lc] * (1.0f / 127.0f);

    const i32x4 zi = {0, 0, 0, 0};

    for (int t = t0; t < t1; ++t) {
        const int rb_ = t & 1;
        const signed char* hr = h2s[rb_];
        signed char* hw = h2s[rb_ ^ 1];

        u16x4 gxv[2][4];
        if (lg < 2) {
#pragma unroll
            for (int hf = 0; hf < 2; ++hf)
#pragma unroll
                for (int g = 0; g < 4; ++g) {
                    const int nt = wid * 8 + hf * 4 + g;
                    size_t addr = ((((size_t)bblk * TC + (t - t0)) * 64 + nt) * 16 + lc) * 8 + 4 * lg;
                    gxv[hf][g] = *(const u16x4*)(gxc + addr);
                }
        }

#pragma unroll
        for (int hf = 0; hf < 2; ++hf) {
            i32x4 ia[4];
#pragma unroll
            for (int g = 0; g < 4; ++g) ia[g] = zi;
#pragma unroll
            for (int ks = 0; ks < 4; ++ks) {
                i32x4 afr = *(const i32x4*)&hr[lc * HP + ks * 64 + lg * 16];
#pragma unroll
                for (int g = 0; g < 4; ++g) {
                    i32x4 w = (ks < 2) ? wreg[ks * 8 + hf * 4 + g]
                            : *(const i32x4*)&wlds[ks - 2][wid * 8 + hf * 4 + g][(size_t)lane * 16];
                    ia[g] = __builtin_amdgcn_mfma_i32_16x16x64_i8(afr, w, ia[g], 0, 0, 0);
                }
            }
            if (lg < 2) {
                const int hcol = wid * 32 + hf * 16 + lc;
#pragma unroll
                for (int r = 0; r < 4; ++r) {
                    const int row = lg * 4 + r;
                    float gi = ss[hf][0] * (float)ia[0][r] + bf2f(gxv[hf][0][r]);
                    float gj = ss[hf][1] * (float)ia[1][r] + bf2f(gxv[hf][1][r]);
                    float gf = ss[hf][2] * (float)ia[2][r] + bf2f(gxv[hf][2][r]);
                    float go = ss[hf][3] * (float)ia[3][r] + bf2f(gxv[hf][3][r]);
                    float cn = c2[hf][r] * sigf(gf + 1.0f) + sigf(gi) * tanhf2(gj);
                    float h  = tanhf2(cn) * sigf(go);
                    c2[hf][r] = cn;
                    hw[row * HP + hcol] = q8(h);
                }
            }
        }
        __syncthreads();
    }

    if (t1 < T_SZ) {
        if (lg < 2) {
#pragma unroll
            for (int hf = 0; hf < 2; ++hf)
#pragma unroll
                for (int r = 0; r < 4; ++r)
                    c2g[(size_t)(b0 + lg * 4 + r) * 256 + wid * 32 + hf * 16 + lc] = c2[hf][r];
        }
        for (int i = tid; i < 8 * 256; i += NTHR) {
            int row = i >> 8, col = i & 255;
            h2p[(size_t)(b0 + row) * 256 + col] = h2s[0][row * HP + col];
        }
        return;
    }

    // ---- loss epilogue (final chunk): final h2 in h2s[0] (t1 even) ----
    const signed char* h2fin = h2s[0];
    for (int pp = tid; pp < 8 * VOCABN; pp += NTHR) {
        int row = pp / VOCABN, v = pp - row * VOCABN;
        float s = bd[v];
        for (int k = 0; k < HID; ++k)
            s += ((float)h2fin[row * HP + k] * (1.0f / 127.0f)) * Wd[k * VOCABN + v];
        logitb[row][v] = s;
    }
    __syncthreads();
    if (tid < 8) {
        float mx = -1e30f;
        for (int v = 0; v < VOCABN; ++v) mx = fmaxf(mx, logitb[tid][v]);
        float s = 0.f;
        for (int v = 0; v < VOCABN; ++v) s += __expf(logitb[tid][v] - mx);
        int lab = labels[b0 + tid];
        lossb[tid] = mx + __logf(s) - logitb[tid][lab];
    }
    __syncthreads();
    if (tid == 0) {
        float s = 0.f;
#pragma unroll
        for (int r = 0; r < 8; ++r) s += lossb[r];
        atomicAdd(out, s * (1.0f / (float)B_SZ));
    }
}

// ===================== launch =====================
extern "C" void kernel_launch(void* const* d_in, const int* in_sizes, int n_in,
                              void* d_out, int out_size, void* d_ws, size_t ws_size,
                              hipStream_t stream)
{
    (void)in_sizes; (void)n_in; (void)out_size;
    const int*   feat   = (const int*)d_in[0];
    const int*   labels = (const int*)d_in[1];
    const float* emb    = (const float*)d_in[2];
    const float* W1     = (const float*)d_in[3];
    const float* b1     = (const float*)d_in[4];
    const float* W2     = (const float*)d_in[5];
    const float* b2     = (const float*)d_in[6];
    const float* Wd     = (const float*)d_in[7];
    const float* bd     = (const float*)d_in[8];
    float* out = (float*)d_out;
    char* ws = (char*)d_ws;

    (void)hipMemsetAsync(d_out, 0, sizeof(float), stream);

    int TC = 2;
    {
        const int tcs[7] = {40, 20, 16, 10, 8, 4, 2};
        for (int i = 0; i < 7; ++i)
            if (FIXED_WS + (size_t)tcs[i] * PER_TC <= ws_size) { TC = tcs[i]; break; }
    }

    signed char* wp8  = (signed char*)(ws + WP8_OFF);
    float*       eg2  = (float*)(ws + EG2_OFF);
    float*       sw   = (float*)(ws + SW_OFF);
    float*       c1g  = (float*)(ws + C1G_OFF);
    float*       c2g  = (float*)(ws + C2G_OFF);
    signed char* h2p  = (signed char*)(ws + H2P_OFF);
    signed char* h1c  = (signed char*)(ws + H1C_OFF);
    unsigned short* gxc = (unsigned short*)(ws + H1C_OFF + (size_t)TC * 524288ull);

    const signed char* wp8A = wp8;                       // W1h
    const signed char* wp8G = wp8 + 262144;              // W2x
    const signed char* wp8B = wp8 + 524288;              // W2h
    const float* swA = sw;
    const float* swG = sw + 1024;
    const float* swB = sw + 2048;

    prep_scale<<<(3 * 1024 + 255) / 256, 256, 0, stream>>>(W1, W2, sw);
    prep_pack<<<(3 * 4 * 64 * 64 + 255) / 256, 256, 0, stream>>>(W1, W2, sw, wp8);
    prep_eg2<<<(VOCABN * 256 + 255) / 256, 256, 0, stream>>>(emb, W1, b1, eg2);

    for (int t0 = 0; t0 < T_SZ; t0 += TC) {
        lstm_l1<<<256, NTHR, 0, stream>>>(feat, wp8A, swA, eg2, h1c, c1g, t0, TC);
        gx_gemm<<<256, NTHR, 0, stream>>>(h1c, wp8G, swG, b2, gxc, TC);
        lstm_l2<<<256, NTHR, 0, stream>>>(wp8B, swB, gxc, labels, Wd, bd,
                                          out, c2g, h2p, t0, TC);
    }
}

// Round 13
// 529.859 us; speedup vs baseline: 3.7851x; 1.4961x over previous
//
#include <hip/hip_runtime.h>
#include <cstdint>

#define B_SZ   2048
#define T_SZ   80
#define VOCABN 80
#define EMBN   8
#define HID    256
#define G4     1024
#define NTHR   512
#define HP     272        // int8 h-tile row pitch (16B-aligned, odd 16B blocks)

typedef __bf16 bf16;
typedef __attribute__((ext_vector_type(4))) int    i32x4;
typedef __attribute__((ext_vector_type(4))) float  f32x4;
typedef __attribute__((ext_vector_type(4))) unsigned short u16x4;

__device__ __forceinline__ float sigf(float x)   { return 1.0f / (1.0f + __expf(-x)); }
__device__ __forceinline__ float tanhf2(float x) { return 1.0f - 2.0f / (__expf(2.0f * x) + 1.0f); }

__device__ __forceinline__ unsigned short f2bf(float f) {
    union { float f; unsigned int u; } v; v.f = f;
    unsigned int u = v.u;
    return (unsigned short)((u + 0x7FFFu + ((u >> 16) & 1u)) >> 16);
}
__device__ __forceinline__ float bf2f(unsigned short h) {
    union { unsigned int u; float f; } v; v.u = ((unsigned int)h) << 16;
    return v.f;
}
__device__ __forceinline__ signed char q8(float h) {
    int q = (int)rintf(h * 127.0f);
    q = q > 127 ? 127 : (q < -127 ? -127 : q);
    return (signed char)q;
}

// ===================== ws layout =====================
#define WP8_OFF  0ull                       // 786432 B
#define EG2_OFF  786432ull                  // 327680 B  eg2[tok][256][4] f32 (emb@W1x + b1)
#define SW_OFF   1114112ull                 // 12288 B   sw[3][1024] f32 column scales
#define C1G_OFF  1126400ull                 // 2 MB  c1 f32 [2048][256]
#define C2G_OFF  3223552ull                 // 2 MB  c2 f32
#define H2P_OFF  5320704ull                 // 512 KB h2 int8 [2048][256]
#define H1C_OFF  5844992ull                 // TC*512KB h1c int8 [b][dt][256]
#define FIXED_WS 5844992ull
#define PER_TC   4718592ull                 // 512KB h1c + 4MB gxc(bf16) per t

// ===================== prep kernels (R12-verbatim, proven) =====================
__global__ void prep_scale(const float* __restrict__ W1, const float* __restrict__ W2,
                           float* __restrict__ sw) {
    int idx = blockIdx.x * blockDim.x + threadIdx.x;
    if (idx >= 3 * 1024) return;
    int s = idx >> 10, c = idx & 1023;
    float m = 0.0f;
    for (int r = 0; r < 256; ++r) {
        float v = (s == 0) ? W1[(EMBN + r) * G4 + c]
                : (s == 1) ? W2[r * G4 + c]
                           : W2[(256 + r) * G4 + c];
        m = fmaxf(m, fabsf(v));
    }
    sw[idx] = m * (1.0f / 127.0f) + 1e-20f;
}

__global__ void prep_pack(const float* __restrict__ W1, const float* __restrict__ W2,
                          const float* __restrict__ sw, signed char* __restrict__ wp8) {
    int idx = blockIdx.x * blockDim.x + threadIdx.x;
    if (idx >= 3 * 4 * 64 * 64) return;
    int lane = idx & 63, nt = (idx >> 6) & 63, ks = (idx >> 12) & 3, s = idx >> 14;
    int lc = lane & 15, lg = lane >> 4;
    int scol = (nt & 3) * 256 + (nt >> 3) * 32 + ((nt >> 2) & 1) * 16 + lc;
    float sc = 1.0f / sw[s * 1024 + scol];
#pragma unroll
    for (int e = 0; e < 16; ++e) {
        int row = ks * 64 + lg * 16 + e;
        float v = (s == 0) ? W1[(EMBN + row) * G4 + scol]
                : (s == 1) ? W2[row * G4 + scol]
                           : W2[(256 + row) * G4 + scol];
        int q = (int)rintf(v * sc);
        q = q > 127 ? 127 : (q < -127 ? -127 : q);
        wp8[(size_t)idx * 16 + e] = (signed char)q;
    }
}

__global__ void prep_eg2(const float* __restrict__ emb, const float* __restrict__ W1,
                         const float* __restrict__ b1, float* __restrict__ eg2) {
    int idx = blockIdx.x * blockDim.x + threadIdx.x;
    if (idx >= VOCABN * 256) return;
    int v = idx >> 8, h = idx & 255;
#pragma unroll
    for (int g = 0; g < 4; ++g) {
        int c = g * 256 + h;
        float s = b1[c];
#pragma unroll
        for (int e = 0; e < EMBN; ++e) s += emb[v * EMBN + e] * W1[e * G4 + c];
        eg2[(size_t)idx * 4 + g] = s;
    }
}

// ===================== kernel A: layer-1 recurrence (int8, lane-split pointwise) =====================
__global__ __launch_bounds__(NTHR, 2)
void lstm_l1(const int* __restrict__ feat,
             const signed char* __restrict__ wp8A, const float* __restrict__ swA,
             const float* __restrict__ eg2,
             signed char* __restrict__ h1c, float* __restrict__ c1g,
             int t0, int TC)
{
    __shared__ __align__(16) signed char wlds[2][64][1024];   // ks 2,3: 128 KB
    __shared__ __align__(16) signed char h1s[2][16 * HP];     // 8.5 KB (rows 8..15 stay 0)
    __shared__ unsigned char toks8[8 * T_SZ];

    const int tid  = threadIdx.x;
    const int lane = tid & 63;
    const int wid  = tid >> 6;
    const int lc   = lane & 15;
    const int lg   = lane >> 4;
    const int hfl  = lg >> 1;      // pointwise: which hf this lane owns
    const int lgl  = lg & 1;       // pointwise: row group
    const int bblk = blockIdx.x;
    const int b0   = bblk * 8;
    const int t1   = t0 + TC;

    for (int i = tid; i < 2 * 16 * HP; i += NTHR) h1s[0][i] = 0;
    for (int i = tid; i < 8 * T_SZ; i += NTHR) {
        int r = i / T_SZ, t = i - r * T_SZ;
        toks8[i] = (unsigned char)feat[(b0 + r) * T_SZ + t];
    }
    for (int i = tid; i < 2 * 64 * 64; i += NTHR)
        *(i32x4*)&wlds[0][0][(size_t)i * 16] =
            *(const i32x4*)&wp8A[(size_t)(2 * 64 * 64 + i) * 16];

    const int hcolp = wid * 32 + hfl * 16 + lc;   // pointwise column
    float c1[4] = {0.f, 0.f, 0.f, 0.f};
    if (t0 > 0) {
        __syncthreads();   // zero-fill complete before carry overwrite
        for (int i = tid; i < 8 * 256; i += NTHR) {
            int row = i >> 8, col = i & 255;
            h1s[0][row * HP + col] = h1c[((size_t)(b0 + row) * TC + (TC - 1)) * 256 + col];
        }
#pragma unroll
        for (int r = 0; r < 4; ++r)
            c1[r] = c1g[(size_t)(b0 + lgl * 4 + r) * 256 + hcolp];
    }
    __syncthreads();

    // registers: slices ks=0,1 for this wave's 8 nt tiles (64 VGPR)
    i32x4 wreg[16];
#pragma unroll
    for (int ks = 0; ks < 2; ++ks)
#pragma unroll
        for (int j = 0; j < 8; ++j)
            wreg[ks * 8 + j] = *(const i32x4*)&wp8A[(size_t)((ks * 64 + wid * 8 + j) * 64 + lane) * 16];

    float ssv[4];
#pragma unroll
    for (int g = 0; g < 4; ++g)
        ssv[g] = swA[g * 256 + hcolp] * (1.0f / 127.0f);

    const i32x4 zi = {0, 0, 0, 0};

    for (int t = t0; t < t1; ++t) {
        const int rb_ = t & 1;
        const signed char* hr = h1s[rb_];
        signed char* hw = h1s[rb_ ^ 1];

        // ---- MFMA phase: both hf tiles, shared A-fragments ----
        i32x4 ia0[4], ia1[4];
#pragma unroll
        for (int g = 0; g < 4; ++g) { ia0[g] = zi; ia1[g] = zi; }
#pragma unroll
        for (int ks = 0; ks < 4; ++ks) {
            i32x4 afr = *(const i32x4*)&hr[lc * HP + ks * 64 + lg * 16];
#pragma unroll
            for (int g = 0; g < 4; ++g) {
                i32x4 w0 = (ks < 2) ? wreg[ks * 8 + g]
                         : *(const i32x4*)&wlds[ks - 2][wid * 8 + g][(size_t)lane * 16];
                ia0[g] = __builtin_amdgcn_mfma_i32_16x16x64_i8(afr, w0, ia0[g], 0, 0, 0);
                i32x4 w1 = (ks < 2) ? wreg[ks * 8 + 4 + g]
                         : *(const i32x4*)&wlds[ks - 2][wid * 8 + 4 + g][(size_t)lane * 16];
                ia1[g] = __builtin_amdgcn_mfma_i32_16x16x64_i8(afr, w1, ia1[g], 0, 0, 0);
            }
        }
        // ---- lane-split pointwise: all 64 lanes, 4 calcs each ----
#pragma unroll
        for (int r = 0; r < 4; ++r) {
            const int row = lgl * 4 + r;
            const int tok = toks8[row * T_SZ + t];
            f32x4 e4 = *(const f32x4*)&eg2[((size_t)tok * 256 + hcolp) * 4];
            float gv[4];
#pragma unroll
            for (int g = 0; g < 4; ++g) {
                int v1  = __shfl(ia1[g][r], lane & 31);
                int sel = hfl ? v1 : ia0[g][r];
                gv[g] = ssv[g] * (float)sel + e4[g];
            }
            float cn = c1[r] * sigf(gv[2] + 1.0f) + sigf(gv[0]) * tanhf2(gv[1]);
            float h  = tanhf2(cn) * sigf(gv[3]);
            c1[r] = cn;
            signed char qv = q8(h);
            hw[row * HP + hcolp] = qv;
            h1c[((size_t)(b0 + row) * TC + (t - t0)) * 256 + hcolp] = qv;
        }
        __syncthreads();
    }
    if (t1 < T_SZ) {
#pragma unroll
        for (int r = 0; r < 4; ++r)
            c1g[(size_t)(b0 + lgl * 4 + r) * 256 + hcolp] = c1[r];
    }
}

// ===================== kernel G: gxc = h1c @ W2x + b2 (R12-verbatim) =====================
__global__ __launch_bounds__(NTHR, 2)
void gx_gemm(const signed char* __restrict__ h1c,
             const signed char* __restrict__ wp8G, const float* __restrict__ swG,
             const float* __restrict__ b2, unsigned short* __restrict__ gxc, int TC)
{
    __shared__ __align__(16) signed char wlds[2][64][1024];   // 128 KB
    __shared__ __align__(16) signed char hbuf[16 * HP];       // 4.3 KB

    const int tid  = threadIdx.x;
    const int lane = tid & 63;
    const int wid  = tid >> 6;
    const int lc   = lane & 15;
    const int lg   = lane >> 4;
    const int bblk = blockIdx.x;

    for (int i = tid; i < 2 * 64 * 64; i += NTHR)
        *(i32x4*)&wlds[0][0][(size_t)i * 16] =
            *(const i32x4*)&wp8G[(size_t)(2 * 64 * 64 + i) * 16];

    i32x4 wreg[16];
#pragma unroll
    for (int ks = 0; ks < 2; ++ks)
#pragma unroll
        for (int j = 0; j < 8; ++j)
            wreg[ks * 8 + j] = *(const i32x4*)&wp8G[(size_t)((ks * 64 + wid * 8 + j) * 64 + lane) * 16];

    float ssg[8], b2v[8];
#pragma unroll
    for (int j = 0; j < 8; ++j) {
        int scol = (j & 3) * 256 + wid * 32 + ((j >> 2) & 1) * 16 + lc;
        ssg[j] = swG[scol] * (1.0f / 127.0f);
        b2v[j] = b2[scol];
    }

    const i32x4 zi = {0, 0, 0, 0};
    const int m    = tid >> 5;            // staging row 0..15 (batch m>>1, dt m&1)
    const int col0 = (tid & 31) * 8;
    const int np   = TC >> 1;

    unsigned long long sreg =
        *(const unsigned long long*)&h1c[((size_t)(bblk * 8 + (m >> 1)) * TC + (m & 1)) * 256 + col0];

    for (int tt = 0; tt < np; ++tt) {
        __syncthreads();
        *(unsigned long long*)&hbuf[m * HP + col0] = sreg;
        __syncthreads();
        if (tt + 1 < np)
            sreg = *(const unsigned long long*)
                &h1c[((size_t)(bblk * 8 + (m >> 1)) * TC + (tt + 1) * 2 + (m & 1)) * 256 + col0];

        i32x4 acc[8];
#pragma unroll
        for (int j = 0; j < 8; ++j) acc[j] = zi;
#pragma unroll
        for (int ks = 0; ks < 4; ++ks) {
            i32x4 afr = *(const i32x4*)&hbuf[lc * HP + ks * 64 + lg * 16];
#pragma unroll
            for (int j = 0; j < 8; ++j) {
                i32x4 w = (ks < 2) ? wreg[ks * 8 + j]
                        : *(const i32x4*)&wlds[ks - 2][wid * 8 + j][(size_t)lane * 16];
                acc[j] = __builtin_amdgcn_mfma_i32_16x16x64_i8(afr, w, acc[j], 0, 0, 0);
            }
        }
#pragma unroll
        for (int j = 0; j < 8; ++j) {
            const int nt = wid * 8 + j;
#pragma unroll
            for (int r = 0; r < 4; ++r) {
                size_t addr = ((((size_t)bblk * TC + tt * 2 + (r & 1)) * 64 + nt) * 16 + lc) * 8
                              + 2 * lg + (r >> 1);
                gxc[addr] = f2bf(ssg[j] * (float)acc[j][r] + b2v[j]);
            }
        }
    }
}

// ===================== kernel B: layer-2 recurrence (lane-split pointwise, + loss) =====================
__global__ __launch_bounds__(NTHR, 2)
void lstm_l2(const signed char* __restrict__ wp8B, const float* __restrict__ swB,
             const unsigned short* __restrict__ gxc,
             const int* __restrict__ labels,
             const float* __restrict__ Wd, const float* __restrict__ bd,
             float* __restrict__ out, float* __restrict__ c2g,
             signed char* __restrict__ h2p, int t0, int TC)
{
    __shared__ __align__(16) signed char wlds[2][64][1024];   // 128 KB
    __shared__ __align__(16) signed char h2s[2][16 * HP];     // 8.5 KB
    __shared__ float logitb[8][VOCABN + 1];
    __shared__ float lossb[8];

    const int tid  = threadIdx.x;
    const int lane = tid & 63;
    const int wid  = tid >> 6;
    const int lc   = lane & 15;
    const int lg   = lane >> 4;
    const int hfl  = lg >> 1;
    const int lgl  = lg & 1;
    const int bblk = blockIdx.x;
    const int b0   = bblk * 8;
    const int t1   = t0 + TC;

    for (int i = tid; i < 2 * 16 * HP; i += NTHR) h2s[0][i] = 0;
    for (int i = tid; i < 2 * 64 * 64; i += NTHR)
        *(i32x4*)&wlds[0][0][(size_t)i * 16] =
            *(const i32x4*)&wp8B[(size_t)(2 * 64 * 64 + i) * 16];

    const int hcolp = wid * 32 + hfl * 16 + lc;
    float c2[4] = {0.f, 0.f, 0.f, 0.f};
    if (t0 > 0) {
        __syncthreads();
        for (int i = tid; i < 8 * 256; i += NTHR) {
            int row = i >> 8, col = i & 255;
            h2s[0][row * HP + col] = h2p[(size_t)(b0 + row) * 256 + col];
        }
#pragma unroll
        for (int r = 0; r < 4; ++r)
            c2[r] = c2g[(size_t)(b0 + lgl * 4 + r) * 256 + hcolp];
    }
    __syncthreads();

    i32x4 wreg[16];
#pragma unroll
    for (int ks = 0; ks < 2; ++ks)
#pragma unroll
        for (int j = 0; j < 8; ++j)
            wreg[ks * 8 + j] = *(const i32x4*)&wp8B[(size_t)((ks * 64 + wid * 8 + j) * 64 + lane) * 16];

    float ssv[4];
#pragma unroll
    for (int g = 0; g < 4; ++g)
        ssv[g] = swB[g * 256 + hcolp] * (1.0f / 127.0f);

    const i32x4 zi = {0, 0, 0, 0};

    for (int t = t0; t < t1; ++t) {
        const int rb_ = t & 1;
        const signed char* hr = h2s[rb_];
        signed char* hw = h2s[rb_ ^ 1];

        // gx loads for this lane's (hfl, rows lgl*4..+3): 4 x u16x4
        u16x4 gxv[4];
#pragma unroll
        for (int g = 0; g < 4; ++g) {
            const int nt = wid * 8 + hfl * 4 + g;
            size_t addr = ((((size_t)bblk * TC + (t - t0)) * 64 + nt) * 16 + lc) * 8 + 4 * lgl;
            gxv[g] = *(const u16x4*)(gxc + addr);
        }

        // ---- MFMA phase: both hf tiles, shared A-fragments ----
        i32x4 ia0[4], ia1[4];
#pragma unroll
        for (int g = 0; g < 4; ++g) { ia0[g] = zi; ia1[g] = zi; }
#pragma unroll
        for (int ks = 0; ks < 4; ++ks) {
            i32x4 afr = *(const i32x4*)&hr[lc * HP + ks * 64 + lg * 16];
#pragma unroll
            for (int g = 0; g < 4; ++g) {
                i32x4 w0 = (ks < 2) ? wreg[ks * 8 + g]
                         : *(const i32x4*)&wlds[ks - 2][wid * 8 + g][(size_t)lane * 16];
                ia0[g] = __builtin_amdgcn_mfma_i32_16x16x64_i8(afr, w0, ia0[g], 0, 0, 0);
                i32x4 w1 = (ks < 2) ? wreg[ks * 8 + 4 + g]
                         : *(const i32x4*)&wlds[ks - 2][wid * 8 + 4 + g][(size_t)lane * 16];
                ia1[g] = __builtin_amdgcn_mfma_i32_16x16x64_i8(afr, w1, ia1[g], 0, 0, 0);
            }
        }
        // ---- lane-split pointwise ----
#pragma unroll
        for (int r = 0; r < 4; ++r) {
            const int row = lgl * 4 + r;
            float gv[4];
#pragma unroll
            for (int g = 0; g < 4; ++g) {
                int v1  = __shfl(ia1[g][r], lane & 31);
                int sel = hfl ? v1 : ia0[g][r];
                gv[g] = ssv[g] * (float)sel + bf2f(gxv[g][r]);
            }
            float cn = c2[r] * sigf(gv[2] + 1.0f) + sigf(gv[0]) * tanhf2(gv[1]);
            float h  = tanhf2(cn) * sigf(gv[3]);
            c2[r] = cn;
            hw[row * HP + hcolp] = q8(h);
        }
        __syncthreads();
    }

    if (t1 < T_SZ) {
#pragma unroll
        for (int r = 0; r < 4; ++r)
            c2g[(size_t)(b0 + lgl * 4 + r) * 256 + hcolp] = c2[r];
        for (int i = tid; i < 8 * 256; i += NTHR) {
            int row = i >> 8, col = i & 255;
            h2p[(size_t)(b0 + row) * 256 + col] = h2s[0][row * HP + col];
        }
        return;
    }

    // ---- loss epilogue (final chunk): final h2 in h2s[0] (t1 even) ----
    const signed char* h2fin = h2s[0];
    for (int pp = tid; pp < 8 * VOCABN; pp += NTHR) {
        int row = pp / VOCABN, v = pp - row * VOCABN;
        float s = bd[v];
        for (int k = 0; k < HID; ++k)
            s += ((float)h2fin[row * HP + k] * (1.0f / 127.0f)) * Wd[k * VOCABN + v];
        logitb[row][v] = s;
    }
    __syncthreads();
    if (tid < 8) {
        float mx = -1e30f;
        for (int v = 0; v < VOCABN; ++v) mx = fmaxf(mx, logitb[tid][v]);
        float s = 0.f;
        for (int v = 0; v < VOCABN; ++v) s += __expf(logitb[tid][v] - mx);
        int lab = labels[b0 + tid];
        lossb[tid] = mx + __logf(s) - logitb[tid][lab];
    }
    __syncthreads();
    if (tid == 0) {
        float s = 0.f;
#pragma unroll
        for (int r = 0; r < 8; ++r) s += lossb[r];
        atomicAdd(out, s * (1.0f / (float)B_SZ));
    }
}

// ===================== launch =====================
extern "C" void kernel_launch(void* const* d_in, const int* in_sizes, int n_in,
                              void* d_out, int out_size, void* d_ws, size_t ws_size,
                              hipStream_t stream)
{
    (void)in_sizes; (void)n_in; (void)out_size;
    const int*   feat   = (const int*)d_in[0];
    const int*   labels = (const int*)d_in[1];
    const float* emb    = (const float*)d_in[2];
    const float* W1     = (const float*)d_in[3];
    const float* b1     = (const float*)d_in[4];
    const float* W2     = (const float*)d_in[5];
    const float* b2     = (const float*)d_in[6];
    const float* Wd     = (const float*)d_in[7];
    const float* bd     = (const float*)d_in[8];
    float* out = (float*)d_out;
    char* ws = (char*)d_ws;

    (void)hipMemsetAsync(d_out, 0, sizeof(float), stream);

    int TC = 2;
    {
        const int tcs[8] = {80, 40, 20, 16, 10, 8, 4, 2};
        for (int i = 0; i < 8; ++i)
            if (FIXED_WS + (size_t)tcs[i] * PER_TC <= ws_size) { TC = tcs[i]; break; }
    }

    signed char* wp8  = (signed char*)(ws + WP8_OFF);
    float*       eg2  = (float*)(ws + EG2_OFF);
    float*       sw   = (float*)(ws + SW_OFF);
    float*       c1g  = (float*)(ws + C1G_OFF);
    float*       c2g  = (float*)(ws + C2G_OFF);
    signed char* h2p  = (signed char*)(ws + H2P_OFF);
    signed char* h1c  = (signed char*)(ws + H1C_OFF);
    unsigned short* gxc = (unsigned short*)(ws + H1C_OFF + (size_t)TC * 524288ull);

    const signed char* wp8A = wp8;                       // W1h
    const signed char* wp8G = wp8 + 262144;              // W2x
    const signed char* wp8B = wp8 + 524288;              // W2h
    const float* swA = sw;
    const float* swG = sw + 1024;
    const float* swB = sw + 2048;

    prep_scale<<<(3 * 1024 + 255) / 256, 256, 0, stream>>>(W1, W2, sw);
    prep_pack<<<(3 * 4 * 64 * 64 + 255) / 256, 256, 0, stream>>>(W1, W2, sw, wp8);
    prep_eg2<<<(VOCABN * 256 + 255) / 256, 256, 0, stream>>>(emb, W1, b1, eg2);

    for (int t0 = 0; t0 < T_SZ; t0 += TC) {
        lstm_l1<<<256, NTHR, 0, stream>>>(feat, wp8A, swA, eg2, h1c, c1g, t0, TC);
        gx_gemm<<<256, NTHR, 0, stream>>>(h1c, wp8G, swG, b2, gxc, TC);
        lstm_l2<<<256, NTHR, 0, stream>>>(wp8B, swB, gxc, labels, Wd, bd,
                                          out, c2g, h2p, t0, TC);
    }
}